// Round 3
// baseline (252.877 us; speedup 1.0000x reference)
//
#include <hip/hip_runtime.h>

#define T_SEQ 512
#define EMB 32
#define HID 128
#define BB 2          // batch rows per block -> 256 blocks (all 256 CUs)
#define LDSW 160      // row stride in bf16 elems: 320B -> write banks spread, read disjoint
#define PF 4          // x prefetch depth (register ring, fully unrolled)

typedef __attribute__((ext_vector_type(8))) short short8;   // 8 bf16 in 4 VGPRs
typedef __attribute__((ext_vector_type(4))) float f32x4;

__device__ __forceinline__ short f2bf(float f) {
  union { float f; unsigned u; } v; v.f = f;
  unsigned r = (v.u + 0x7FFFu + ((v.u >> 16) & 1u)) >> 16;  // RNE
  return (short)r;
}

__device__ __forceinline__ float tanh_fast(float a) {
  // tanh(a) = 1 - 2/(exp(2a)+1); exp->v_exp_f32, rcp->v_rcp_f32.
  float e = __expf(2.0f * a);
  return 1.0f - 2.0f * __builtin_amdgcn_rcpf(e + 1.0f);
}

#define MFMA(a, b, c) __builtin_amdgcn_mfma_f32_16x16x32_bf16((a), (b), (c), 0, 0, 0)

__global__ __launch_bounds__(256) void rnn_fused_kernel(
    const float* __restrict__ x, const float* __restrict__ Wx,
    const float* __restrict__ Wh, const float* __restrict__ bh,
    float* __restrict__ out) {
  // h state (bf16), double buffered; only 2 batch rows live here.
  // A-frag rows are duplicated via (lm&1) read addressing (same-addr broadcast).
  __shared__ short hbuf[2][BB][LDSW];

  const int tid = threadIdx.x;
  const int wid = tid >> 6;        // wave 0..3, owns cols [32w, 32w+32)
  const int lane = tid & 63;
  const int l4 = lane >> 4;        // 0..3
  const int lm = lane & 15;        // 0..15
  const int row0 = blockIdx.x * BB;
  const int colbase = wid * 32;

  for (int i = tid; i < 2 * BB * LDSW; i += 256) ((short*)hbuf)[i] = 0;

  // ---- one-time: weight B-fragments into registers ----
  // B-frag layout (16x16x32): lane holds col = lane&15, k = (lane>>4)*8 + j
  short8 whf[2][4];  // [n-tile][k-step]
  short8 wxf[2];
  float bv[2];
#pragma unroll
  for (int nt = 0; nt < 2; ++nt) {
    const int col = colbase + 16 * nt + lm;
    bv[nt] = bh[col];
#pragma unroll
    for (int kb = 0; kb < 4; ++kb) {
      short8 f;
#pragma unroll
      for (int j = 0; j < 8; ++j)
        f[j] = f2bf(Wh[(size_t)(32 * kb + 8 * l4 + j) * HID + col]);
      whf[nt][kb] = f;
    }
    short8 fx;
#pragma unroll
    for (int j = 0; j < 8; ++j)
      fx[j] = f2bf(Wx[(size_t)(8 * l4 + j) * HID + col]);
    wxf[nt] = fx;
  }

  // ---- x prefetch ring: PF steps deep; A-frag row lm holds batch row (lm&1) ----
  const int xrow = row0 + (lm & 1);
  const float* xptr = x + (size_t)xrow * T_SEQ * EMB + 8 * l4;
  f32x4 xf0[PF], xf1[PF];
#pragma unroll
  for (int p = 0; p < PF; ++p) {
    xf0[p] = *(const f32x4*)(xptr + (size_t)p * EMB);
    xf1[p] = *(const f32x4*)(xptr + (size_t)p * EMB + 4);
  }

  // ---- per-lane output assignment: every lane owns ONE (row,col) ----
  const int rsel = l4 & 1;         // batch row parity
  const int csel = l4 >> 1;        // which 16-col tile
  const int ocol = colbase + 16 * csel + lm;
  float* outp = out + (size_t)(row0 + rsel) * T_SEQ * HID + ocol;
  float* hfinp = out + (size_t)512 * T_SEQ * HID + (size_t)(row0 + rsel) * HID + ocol;

  __syncthreads();  // LDS zero-init complete (full barrier OK once)

  for (int tb = 0; tb < T_SEQ; tb += PF) {
#pragma unroll
    for (int i = 0; i < PF; ++i) {
      const int t = tb + i;
      const int cur = t & 1, prev = cur ^ 1;

      // h A-frags first (longest latency); row = lm&1 (broadcast duplicates)
      const short* hb = &hbuf[prev][lm & 1][0];
      short8 ah[4];
#pragma unroll
      for (int kb = 0; kb < 4; ++kb)
        ah[kb] = *(const short8*)(hb + 32 * kb + 8 * l4);

      // convert ring slot i (loaded PF steps ago -> long since landed)
      short8 xa;
#pragma unroll
      for (int j = 0; j < 4; ++j) { xa[j] = f2bf(xf0[i][j]); xa[4 + j] = f2bf(xf1[i][j]); }

      // refill slot i for step t+PF (stays in flight across PF barriers)
      if (t + PF < T_SEQ) {
        xf0[i] = *(const f32x4*)(xptr + (size_t)(t + PF) * EMB);
        xf1[i] = *(const f32x4*)(xptr + (size_t)(t + PF) * EMB + 4);
      }

      // split accumulate chains: (x,kb0,kb1) || (kb2,kb3)
      f32x4 acc0a = {bv[0], bv[0], bv[0], bv[0]};
      f32x4 acc1a = {bv[1], bv[1], bv[1], bv[1]};
      f32x4 acc0b = {0.f, 0.f, 0.f, 0.f};
      f32x4 acc1b = {0.f, 0.f, 0.f, 0.f};
      acc0a = MFMA(xa, wxf[0], acc0a);
      acc1a = MFMA(xa, wxf[1], acc1a);
      acc0a = MFMA(ah[0], whf[0][0], acc0a);
      acc1a = MFMA(ah[0], whf[1][0], acc1a);
      acc0a = MFMA(ah[1], whf[0][1], acc0a);
      acc1a = MFMA(ah[1], whf[1][1], acc1a);
      acc0b = MFMA(ah[2], whf[0][2], acc0b);
      acc1b = MFMA(ah[2], whf[1][2], acc1b);
      acc0b = MFMA(ah[3], whf[0][3], acc0b);
      acc1b = MFMA(ah[3], whf[1][3], acc1b);

      // each lane extracts its one value (compile-time element indices only)
      float v0 = (rsel ? acc0a[1] : acc0a[0]) + (rsel ? acc0b[1] : acc0b[0]);
      float v1 = (rsel ? acc1a[1] : acc1a[0]) + (rsel ? acc1b[1] : acc1b[0]);
      float v = csel ? v1 : v0;
      float th = tanh_fast(v);

      hbuf[cur][rsel][ocol] = f2bf(th);   // 1 ds_write_b16 per lane
      outp[(size_t)t * HID] = th;          // 1 global store per lane
      if (t == T_SEQ - 1) *hfinp = th;

      // LDS visibility only — do NOT drain global stores/loads (no vmcnt wait!)
      asm volatile("s_waitcnt lgkmcnt(0)\n\ts_barrier" ::: "memory");
    }
  }
}

extern "C" void kernel_launch(void* const* d_in, const int* in_sizes, int n_in,
                              void* d_out, int out_size, void* d_ws, size_t ws_size,
                              hipStream_t stream) {
  const float* x  = (const float*)d_in[0];
  const float* Wx = (const float*)d_in[1];
  const float* Wh = (const float*)d_in[2];
  const float* bh = (const float*)d_in[3];
  float* out = (float*)d_out;
  (void)in_sizes; (void)n_in; (void)out_size; (void)d_ws; (void)ws_size;
  rnn_fused_kernel<<<512 / BB, 256, 0, stream>>>(x, Wx, Wh, bh, out);
}

// Round 4
// 249.849 us; speedup vs baseline: 1.0121x; 1.0121x over previous
//
#include <hip/hip_runtime.h>

#define T_SEQ 512
#define EMB 32
#define HID 128
#define BB 2          // batch rows per recurrence block -> 256 blocks
#define LDSW 160      // row stride in bf16 elems
#define PF 4          // xw prefetch ring depth
#define GROWS 64      // bt-rows per GEMM block -> 4096 blocks

typedef __attribute__((ext_vector_type(8))) short short8;   // 8 bf16
typedef __attribute__((ext_vector_type(4))) float f32x4;

__device__ __forceinline__ short f2bf(float f) {
  union { float f; unsigned u; } v; v.f = f;
  unsigned r = (v.u + 0x7FFFu + ((v.u >> 16) & 1u)) >> 16;  // RNE
  return (short)r;
}

__device__ __forceinline__ float bf2f(unsigned short u) {
  union { unsigned u; float f; } c; c.u = ((unsigned)u) << 16; return c.f;
}

__device__ __forceinline__ float tanh_fast(float a) {
  float e = __expf(2.0f * a);
  return 1.0f - 2.0f * __builtin_amdgcn_rcpf(e + 1.0f);
}

#define MFMA(a, b, c) __builtin_amdgcn_mfma_f32_16x16x32_bf16((a), (b), (c), 0, 0, 0)

// ---------------- Kernel 1: xw[bt][c] = x[bt][:] @ Wx + bh  (bf16) ----------------
__global__ __launch_bounds__(256) void xw_gemm_kernel(
    const float* __restrict__ x, const float* __restrict__ Wx,
    const float* __restrict__ bh, unsigned short* __restrict__ xw) {
  const int tid = threadIdx.x;
  const int wid = tid >> 6;
  const int lane = tid & 63;
  const int l4 = lane >> 4, lm = lane & 15;
  const int colbase = wid * 32;

  short8 wxf[2]; float bv[2];
#pragma unroll
  for (int nt = 0; nt < 2; ++nt) {
    const int col = colbase + 16 * nt + lm;
    bv[nt] = bh[col];
    short8 fx;
#pragma unroll
    for (int j = 0; j < 8; ++j)
      fx[j] = f2bf(Wx[(size_t)(8 * l4 + j) * HID + col]);
    wxf[nt] = fx;
  }

  const size_t row0 = (size_t)blockIdx.x * GROWS;
#pragma unroll
  for (int mt = 0; mt < GROWS / 16; ++mt) {
    const size_t arow = row0 + mt * 16 + lm;
    const float* xp = x + arow * EMB + 8 * l4;
    f32x4 xf0 = *(const f32x4*)xp;
    f32x4 xf1 = *(const f32x4*)(xp + 4);
    short8 xa;
#pragma unroll
    for (int j = 0; j < 4; ++j) { xa[j] = f2bf(xf0[j]); xa[4 + j] = f2bf(xf1[j]); }
    f32x4 acc0 = {bv[0], bv[0], bv[0], bv[0]};
    f32x4 acc1 = {bv[1], bv[1], bv[1], bv[1]};
    acc0 = MFMA(xa, wxf[0], acc0);
    acc1 = MFMA(xa, wxf[1], acc1);
    unsigned short* op = xw + (row0 + mt * 16 + 4 * l4) * HID;
#pragma unroll
    for (int r = 0; r < 4; ++r) {
      op[(size_t)r * HID + colbase + lm]      = (unsigned short)f2bf(acc0[r]);
      op[(size_t)r * HID + colbase + 16 + lm] = (unsigned short)f2bf(acc1[r]);
    }
  }
}

// ---------------- Kernel 2: slim serial recurrence ----------------
__global__ __launch_bounds__(256) void rnn_rec_kernel(
    const unsigned short* __restrict__ xw, const float* __restrict__ Wh,
    float* __restrict__ out) {
  __shared__ short hbuf[2][BB][LDSW];

  const int tid = threadIdx.x;
  const int wid = tid >> 6;
  const int lane = tid & 63;
  const int l4 = lane >> 4, lm = lane & 15;
  const int row0 = blockIdx.x * BB;
  const int colbase = wid * 32;

  for (int i = tid; i < 2 * BB * LDSW; i += 256) ((short*)hbuf)[i] = 0;

  short8 whf[2][4];
#pragma unroll
  for (int nt = 0; nt < 2; ++nt) {
    const int col = colbase + 16 * nt + lm;
#pragma unroll
    for (int kb = 0; kb < 4; ++kb) {
      short8 f;
#pragma unroll
      for (int j = 0; j < 8; ++j)
        f[j] = f2bf(Wh[(size_t)(32 * kb + 8 * l4 + j) * HID + col]);
      whf[nt][kb] = f;
    }
  }

  const int rsel = l4 & 1;
  const int csel = l4 >> 1;
  const int ocol = colbase + 16 * csel + lm;

  // xw ring: lane streams xw[(row0+rsel)*T + t][ocol]
  const unsigned short* xwp = xw + ((size_t)(row0 + rsel) * T_SEQ) * HID + ocol;
  unsigned short xr[PF];
#pragma unroll
  for (int p = 0; p < PF; ++p) xr[p] = xwp[(size_t)p * HID];

  float* outp = out + (size_t)(row0 + rsel) * T_SEQ * HID + ocol;
  float* hfinp = out + (size_t)512 * T_SEQ * HID + (size_t)(row0 + rsel) * HID + ocol;

  // precomputed LDS pointers (cur parity resolved at compile time under unroll)
  const short* hr[2] = { &hbuf[0][lm & 1][0], &hbuf[1][lm & 1][0] };
  short* hw[2] = { &hbuf[0][rsel][ocol], &hbuf[1][rsel][ocol] };

  __syncthreads();

#pragma unroll 4
  for (int t = 0; t < T_SEQ; ++t) {
    const int cur = t & 1, prev = cur ^ 1, slot = t & 3;

    // h A-frags first (head of the serial chain)
    const short* hb = hr[prev];
    short8 ah[4];
#pragma unroll
    for (int kb = 0; kb < 4; ++kb)
      ah[kb] = *(const short8*)(hb + 32 * kb + 8 * l4);

    // consume + refill xw ring (off the dependency chain)
    const unsigned short xv = xr[slot];
    if (t + PF < T_SEQ) xr[slot] = xwp[(size_t)PF * HID];
    xwp += HID;

    // 8 MFMAs, four independent depth-2 chains
    const f32x4 z = {0.f, 0.f, 0.f, 0.f};
    f32x4 a0 = MFMA(ah[0], whf[0][0], z);
    f32x4 a1 = MFMA(ah[0], whf[1][0], z);
    f32x4 b0 = MFMA(ah[2], whf[0][2], z);
    f32x4 b1 = MFMA(ah[2], whf[1][2], z);
    a0 = MFMA(ah[1], whf[0][1], a0);
    a1 = MFMA(ah[1], whf[1][1], a1);
    b0 = MFMA(ah[3], whf[0][3], b0);
    b1 = MFMA(ah[3], whf[1][3], b1);

    // per-lane extraction (compile-time element indices)
    float vA0 = rsel ? a0[1] : a0[0];
    float vB0 = rsel ? b0[1] : b0[0];
    float vA1 = rsel ? a1[1] : a1[0];
    float vB1 = rsel ? b1[1] : b1[0];
    float s0 = vA0 + vB0;
    float s1 = vA1 + vB1;
    float v = (csel ? s1 : s0) + bf2f(xv);
    float th = tanh_fast(v);

    *(cur ? hw[1] : hw[0]) = f2bf(th);   // 1 ds_write_b16
    *outp = th; outp += HID;             // 1 global store (no vmcnt wait)
    if (t == T_SEQ - 1) *hfinp = th;

    asm volatile("s_waitcnt lgkmcnt(0)\n\ts_barrier" ::: "memory");
  }
}

// ---------------- Fallback (round-2 fused kernel) if ws too small ----------------
__global__ __launch_bounds__(256) void rnn_fused_fallback(
    const float* __restrict__ x, const float* __restrict__ Wx,
    const float* __restrict__ Wh, const float* __restrict__ bh,
    float* __restrict__ out) {
  __shared__ short hbuf[2][BB][LDSW];
  const int tid = threadIdx.x;
  const int wid = tid >> 6;
  const int lane = tid & 63;
  const int l4 = lane >> 4, lm = lane & 15;
  const int row0 = blockIdx.x * BB;
  const int colbase = wid * 32;
  for (int i = tid; i < 2 * BB * LDSW; i += 256) ((short*)hbuf)[i] = 0;
  short8 whf[2][4]; short8 wxf[2]; float bv[2];
#pragma unroll
  for (int nt = 0; nt < 2; ++nt) {
    const int col = colbase + 16 * nt + lm;
    bv[nt] = bh[col];
#pragma unroll
    for (int kb = 0; kb < 4; ++kb) {
      short8 f;
#pragma unroll
      for (int j = 0; j < 8; ++j)
        f[j] = f2bf(Wh[(size_t)(32 * kb + 8 * l4 + j) * HID + col]);
      whf[nt][kb] = f;
    }
    short8 fx;
#pragma unroll
    for (int j = 0; j < 8; ++j)
      fx[j] = f2bf(Wx[(size_t)(8 * l4 + j) * HID + col]);
    wxf[nt] = fx;
  }
  const int xrow = row0 + (lm & 1);
  const float* xptr = x + (size_t)xrow * T_SEQ * EMB + 8 * l4;
  f32x4 xf0 = *(const f32x4*)(xptr);
  f32x4 xf1 = *(const f32x4*)(xptr + 4);
  const int rsel = l4 & 1, csel = l4 >> 1;
  const int ocol = colbase + 16 * csel + lm;
  float* outp = out + (size_t)(row0 + rsel) * T_SEQ * HID + ocol;
  float* hfinp = out + (size_t)512 * T_SEQ * HID + (size_t)(row0 + rsel) * HID + ocol;
  __syncthreads();
#pragma unroll 2
  for (int t = 0; t < T_SEQ; ++t) {
    const int cur = t & 1, prev = cur ^ 1;
    const short* hb = &hbuf[prev][lm & 1][0];
    short8 ah[4];
#pragma unroll
    for (int kb = 0; kb < 4; ++kb)
      ah[kb] = *(const short8*)(hb + 32 * kb + 8 * l4);
    short8 xa;
#pragma unroll
    for (int j = 0; j < 4; ++j) { xa[j] = f2bf(xf0[j]); xa[4 + j] = f2bf(xf1[j]); }
    if (t + 1 < T_SEQ) {
      xf0 = *(const f32x4*)(xptr + (size_t)(t + 1) * EMB);
      xf1 = *(const f32x4*)(xptr + (size_t)(t + 1) * EMB + 4);
    }
    f32x4 acc0a = {bv[0], bv[0], bv[0], bv[0]};
    f32x4 acc1a = {bv[1], bv[1], bv[1], bv[1]};
    f32x4 acc0b = {0.f, 0.f, 0.f, 0.f};
    f32x4 acc1b = {0.f, 0.f, 0.f, 0.f};
    acc0a = MFMA(xa, wxf[0], acc0a);
    acc1a = MFMA(xa, wxf[1], acc1a);
    acc0a = MFMA(ah[0], whf[0][0], acc0a);
    acc1a = MFMA(ah[0], whf[1][0], acc1a);
    acc0a = MFMA(ah[1], whf[0][1], acc0a);
    acc1a = MFMA(ah[1], whf[1][1], acc1a);
    acc0b = MFMA(ah[2], whf[0][2], acc0b);
    acc1b = MFMA(ah[2], whf[1][2], acc1b);
    acc0b = MFMA(ah[3], whf[0][3], acc0b);
    acc1b = MFMA(ah[3], whf[1][3], acc1b);
    float v0 = (rsel ? acc0a[1] : acc0a[0]) + (rsel ? acc0b[1] : acc0b[0]);
    float v1 = (rsel ? acc1a[1] : acc1a[0]) + (rsel ? acc1b[1] : acc1b[0]);
    float v = csel ? v1 : v0;
    float th = tanh_fast(v);
    hbuf[cur][rsel][ocol] = f2bf(th);
    *outp = th; outp += HID;
    if (t == T_SEQ - 1) *hfinp = th;
    asm volatile("s_waitcnt lgkmcnt(0)\n\ts_barrier" ::: "memory");
  }
}

extern "C" void kernel_launch(void* const* d_in, const int* in_sizes, int n_in,
                              void* d_out, int out_size, void* d_ws, size_t ws_size,
                              hipStream_t stream) {
  const float* x  = (const float*)d_in[0];
  const float* Wx = (const float*)d_in[1];
  const float* Wh = (const float*)d_in[2];
  const float* bh = (const float*)d_in[3];
  float* out = (float*)d_out;
  (void)in_sizes; (void)n_in; (void)out_size;

  const size_t need = (size_t)512 * T_SEQ * HID * sizeof(unsigned short);  // 67 MB
  if (ws_size >= need) {
    unsigned short* xw = (unsigned short*)d_ws;
    xw_gemm_kernel<<<(512 * T_SEQ) / GROWS, 256, 0, stream>>>(x, Wx, bh, xw);
    rnn_rec_kernel<<<512 / BB, 256, 0, stream>>>(xw, Wh, out);
  } else {
    rnn_fused_fallback<<<512 / BB, 256, 0, stream>>>(x, Wx, Wh, bh, out);
  }
}

// Round 6
// 140.507 us; speedup vs baseline: 1.7997x; 1.7782x over previous
//
#include <hip/hip_runtime.h>

#define T_SEQ 512
#define EMB 32
#define HID 128
#define BB 2          // batch rows per recurrence block -> 256 blocks
#define LDSW 160      // row stride in bf16 elems
#define PF 4          // xw prefetch ring depth (4 named regs, asm-managed)
#define GROWS 64      // bt-rows per GEMM block -> 4096 blocks

typedef __attribute__((ext_vector_type(8))) short short8;   // 8 bf16
typedef __attribute__((ext_vector_type(4))) float f32x4;

__device__ __forceinline__ short f2bf(float f) {
  union { float f; unsigned u; } v; v.f = f;
  unsigned r = (v.u + 0x7FFFu + ((v.u >> 16) & 1u)) >> 16;  // RNE
  return (short)r;
}

__device__ __forceinline__ float bf2f(unsigned short u) {
  union { unsigned u; float f; } c; c.u = ((unsigned)u) << 16; return c.f;
}

__device__ __forceinline__ float tanh_fast(float a) {
  float e = __expf(2.0f * a);
  return 1.0f - 2.0f * __builtin_amdgcn_rcpf(e + 1.0f);
}

#define MFMA(a, b, c) __builtin_amdgcn_mfma_f32_16x16x32_bf16((a), (b), (c), 0, 0, 0)

// ---------------- Kernel 1: xw[bt][c] = x[bt][:] @ Wx + bh  (bf16) ----------------
__global__ __launch_bounds__(256) void xw_gemm_kernel(
    const float* __restrict__ x, const float* __restrict__ Wx,
    const float* __restrict__ bh, unsigned short* __restrict__ xw) {
  const int tid = threadIdx.x;
  const int wid = tid >> 6;
  const int lane = tid & 63;
  const int l4 = lane >> 4, lm = lane & 15;
  const int colbase = wid * 32;

  short8 wxf[2]; float bv[2];
#pragma unroll
  for (int nt = 0; nt < 2; ++nt) {
    const int col = colbase + 16 * nt + lm;
    bv[nt] = bh[col];
    short8 fx;
#pragma unroll
    for (int j = 0; j < 8; ++j)
      fx[j] = f2bf(Wx[(size_t)(8 * l4 + j) * HID + col]);
    wxf[nt] = fx;
  }

  const size_t row0 = (size_t)blockIdx.x * GROWS;
#pragma unroll
  for (int mt = 0; mt < GROWS / 16; ++mt) {
    const size_t arow = row0 + mt * 16 + lm;
    const float* xp = x + arow * EMB + 8 * l4;
    f32x4 xf0 = *(const f32x4*)xp;
    f32x4 xf1 = *(const f32x4*)(xp + 4);
    short8 xa;
#pragma unroll
    for (int j = 0; j < 4; ++j) { xa[j] = f2bf(xf0[j]); xa[4 + j] = f2bf(xf1[j]); }
    f32x4 acc0 = {bv[0], bv[0], bv[0], bv[0]};
    f32x4 acc1 = {bv[1], bv[1], bv[1], bv[1]};
    acc0 = MFMA(xa, wxf[0], acc0);
    acc1 = MFMA(xa, wxf[1], acc1);
    unsigned short* op = xw + (row0 + mt * 16 + 4 * l4) * HID;
#pragma unroll
    for (int r = 0; r < 4; ++r) {
      op[(size_t)r * HID + colbase + lm]      = (unsigned short)f2bf(acc0[r]);
      op[(size_t)r * HID + colbase + 16 + lm] = (unsigned short)f2bf(acc1[r]);
    }
  }
}

// ---------------- Kernel 2: slim serial recurrence (asm-counted vmem) ----------------
__global__ __launch_bounds__(256) void rnn_rec_kernel(
    const unsigned short* __restrict__ xw, const float* __restrict__ Wh,
    float* __restrict__ out) {
  __shared__ short hbuf[2][BB][LDSW];

  const int tid = threadIdx.x;
  const int wid = tid >> 6;
  const int lane = tid & 63;
  const int l4 = lane >> 4, lm = lane & 15;
  const int row0 = blockIdx.x * BB;
  const int colbase = wid * 32;

  for (int i = tid; i < 2 * BB * LDSW; i += 256) ((short*)hbuf)[i] = 0;

  short8 whf[2][4];
#pragma unroll
  for (int nt = 0; nt < 2; ++nt) {
    const int col = colbase + 16 * nt + lm;
#pragma unroll
    for (int kb = 0; kb < 4; ++kb) {
      short8 f;
#pragma unroll
      for (int j = 0; j < 8; ++j)
        f[j] = f2bf(Wh[(size_t)(32 * kb + 8 * l4 + j) * HID + col]);
      whf[nt][kb] = f;
    }
  }

  const int rsel = l4 & 1;
  const int csel = l4 >> 1;
  const int ocol = colbase + 16 * csel + lm;

  // byte offsets (fit u32: xw 67MB, out 134MB)
  const unsigned xw_off0  = ((unsigned)(row0 + rsel) * T_SEQ) * (HID * 2) + (unsigned)ocol * 2;
  const unsigned out_off0 = ((unsigned)(row0 + rsel) * T_SEQ) * (HID * 4) + (unsigned)ocol * 4;
  const unsigned short* xwb = xw;
  float* outb = out;
  float* hfinp = out + (size_t)512 * T_SEQ * HID + (size_t)(row0 + rsel) * HID + ocol;

  // LDS pointers: read row (lm&1) with +8*l4 k-offset folded; write own (rsel,ocol)
  const short* hr0 = &hbuf[0][lm & 1][8 * l4];
  const short* hr1 = &hbuf[1][lm & 1][8 * l4];
  short* hw0 = &hbuf[0][rsel][ocol];
  short* hw1 = &hbuf[1][rsel][ocol];

  // prologue: L0..L3 in flight (4 outstanding loads, 0 stores)
  unsigned xr0, xr1, xr2, xr3;
  asm volatile("global_load_ushort %0, %1, %2" : "=v"(xr0) : "v"(xw_off0 + 0u * 256u), "s"(xwb));
  asm volatile("global_load_ushort %0, %1, %2" : "=v"(xr1) : "v"(xw_off0 + 1u * 256u), "s"(xwb));
  asm volatile("global_load_ushort %0, %1, %2" : "=v"(xr2) : "v"(xw_off0 + 2u * 256u), "s"(xwb));
  asm volatile("global_load_ushort %0, %1, %2" : "=v"(xr3) : "v"(xw_off0 + 3u * 256u), "s"(xwb));

  float th_last = 0.f;

  __syncthreads();  // zero-init visible

  // Per step, fixed vmem issue order: [wait vmcnt(WN) + in-asm reg read]
  // [refill load] ... [store]. Steady state: 7 ops (4 loads + 3 stores)
  // outstanding-after-L(t) -> vmcnt(7) retires exactly L(t).
  // NOTE: the XR read happens INSIDE the wait asm ("=&v" early-clobber so the
  // copy can never share XR's register with the in-flight refill load).
#define RSTEP(T, PAR, WN, XR) do {                                               \
    const short* hb_ = (PAR) ? hr0 : hr1;   /* prev = PAR^1 */                   \
    short8 ah0 = *(const short8*)(hb_ + 0);                                      \
    short8 ah1 = *(const short8*)(hb_ + 32);                                     \
    short8 ah2 = *(const short8*)(hb_ + 64);                                     \
    short8 ah3 = *(const short8*)(hb_ + 96);                                     \
    unsigned xv_;                                                                \
    asm volatile("s_waitcnt vmcnt(" #WN ")\n\tv_mov_b32 %0, %1"                  \
                 : "=&v"(xv_) : "v"(XR));                                        \
    int tl_ = (T) + PF; if (tl_ > T_SEQ - 1) tl_ = T_SEQ - 1;                    \
    asm volatile("global_load_ushort %0, %1, %2"                                 \
                 : "=v"(XR) : "v"(xw_off0 + (unsigned)tl_ * 256u), "s"(xwb));    \
    const f32x4 z_ = {0.f, 0.f, 0.f, 0.f};                                       \
    f32x4 a0 = MFMA(ah0, whf[0][0], z_);                                         \
    f32x4 a1 = MFMA(ah0, whf[1][0], z_);                                         \
    f32x4 b0 = MFMA(ah2, whf[0][2], z_);                                         \
    f32x4 b1 = MFMA(ah2, whf[1][2], z_);                                         \
    a0 = MFMA(ah1, whf[0][1], a0);                                               \
    a1 = MFMA(ah1, whf[1][1], a1);                                               \
    b0 = MFMA(ah3, whf[0][3], b0);                                               \
    b1 = MFMA(ah3, whf[1][3], b1);                                               \
    float vA0 = rsel ? a0[1] : a0[0];                                            \
    float vB0 = rsel ? b0[1] : b0[0];                                            \
    float vA1 = rsel ? a1[1] : a1[0];                                            \
    float vB1 = rsel ? b1[1] : b1[0];                                            \
    float v_ = (csel ? (vA1 + vB1) : (vA0 + vB0)) + bf2f((unsigned short)xv_);   \
    float th_ = tanh_fast(v_);                                                   \
    *((PAR) ? hw1 : hw0) = f2bf(th_);   /* cur = PAR */                          \
    asm volatile("global_store_dword %0, %1, %2"                                 \
                 :: "v"(out_off0 + (unsigned)(T) * 512u), "v"(th_), "s"(outb));  \
    th_last = th_;                                                               \
    asm volatile("s_waitcnt lgkmcnt(0)\n\ts_barrier" ::: "memory");              \
  } while (0)

  // peel: exact counts while the load/store pattern fills
  RSTEP(0, 0, 3, xr0);
  RSTEP(1, 1, 4, xr1);
  RSTEP(2, 0, 5, xr2);
  RSTEP(3, 1, 6, xr3);
  for (int tb = 4; tb < T_SEQ; tb += 4) {
    RSTEP(tb + 0, 0, 7, xr0);
    RSTEP(tb + 1, 1, 7, xr1);
    RSTEP(tb + 2, 0, 7, xr2);
    RSTEP(tb + 3, 1, 7, xr3);
  }
#undef RSTEP

  *hfinp = th_last;  // final h (t = T-1), unconditional, off the loop
}

// ---------------- Fallback (round-2 fused kernel) if ws too small ----------------
__global__ __launch_bounds__(256) void rnn_fused_fallback(
    const float* __restrict__ x, const float* __restrict__ Wx,
    const float* __restrict__ Wh, const float* __restrict__ bh,
    float* __restrict__ out) {
  __shared__ short hbuf[2][BB][LDSW];
  const int tid = threadIdx.x;
  const int wid = tid >> 6;
  const int lane = tid & 63;
  const int l4 = lane >> 4, lm = lane & 15;
  const int row0 = blockIdx.x * BB;
  const int colbase = wid * 32;
  for (int i = tid; i < 2 * BB * LDSW; i += 256) ((short*)hbuf)[i] = 0;
  short8 whf[2][4]; short8 wxf[2]; float bv[2];
#pragma unroll
  for (int nt = 0; nt < 2; ++nt) {
    const int col = colbase + 16 * nt + lm;
    bv[nt] = bh[col];
#pragma unroll
    for (int kb = 0; kb < 4; ++kb) {
      short8 f;
#pragma unroll
      for (int j = 0; j < 8; ++j)
        f[j] = f2bf(Wh[(size_t)(32 * kb + 8 * l4 + j) * HID + col]);
      whf[nt][kb] = f;
    }
    short8 fx;
#pragma unroll
    for (int j = 0; j < 8; ++j)
      fx[j] = f2bf(Wx[(size_t)(8 * l4 + j) * HID + col]);
    wxf[nt] = fx;
  }
  const int xrow = row0 + (lm & 1);
  const float* xptr = x + (size_t)xrow * T_SEQ * EMB + 8 * l4;
  f32x4 xf0 = *(const f32x4*)(xptr);
  f32x4 xf1 = *(const f32x4*)(xptr + 4);
  const int rsel = l4 & 1, csel = l4 >> 1;
  const int ocol = colbase + 16 * csel + lm;
  float* outp = out + (size_t)(row0 + rsel) * T_SEQ * HID + ocol;
  float* hfinp = out + (size_t)512 * T_SEQ * HID + (size_t)(row0 + rsel) * HID + ocol;
  __syncthreads();
#pragma unroll 2
  for (int t = 0; t < T_SEQ; ++t) {
    const int cur = t & 1, prev = cur ^ 1;
    const short* hb = &hbuf[prev][lm & 1][0];
    short8 ah[4];
#pragma unroll
    for (int kb = 0; kb < 4; ++kb)
      ah[kb] = *(const short8*)(hb + 32 * kb + 8 * l4);
    short8 xa;
#pragma unroll
    for (int j = 0; j < 4; ++j) { xa[j] = f2bf(xf0[j]); xa[4 + j] = f2bf(xf1[j]); }
    if (t + 1 < T_SEQ) {
      xf0 = *(const f32x4*)(xptr + (size_t)(t + 1) * EMB);
      xf1 = *(const f32x4*)(xptr + (size_t)(t + 1) * EMB + 4);
    }
    f32x4 acc0a = {bv[0], bv[0], bv[0], bv[0]};
    f32x4 acc1a = {bv[1], bv[1], bv[1], bv[1]};
    f32x4 acc0b = {0.f, 0.f, 0.f, 0.f};
    f32x4 acc1b = {0.f, 0.f, 0.f, 0.f};
    acc0a = MFMA(xa, wxf[0], acc0a);
    acc1a = MFMA(xa, wxf[1], acc1a);
    acc0a = MFMA(ah[0], whf[0][0], acc0a);
    acc1a = MFMA(ah[0], whf[1][0], acc1a);
    acc0a = MFMA(ah[1], whf[0][1], acc0a);
    acc1a = MFMA(ah[1], whf[1][1], acc1a);
    acc0b = MFMA(ah[2], whf[0][2], acc0b);
    acc1b = MFMA(ah[2], whf[1][2], acc1b);
    acc0b = MFMA(ah[3], whf[0][3], acc0b);
    acc1b = MFMA(ah[3], whf[1][3], acc1b);
    float v0 = (rsel ? acc0a[1] : acc0a[0]) + (rsel ? acc0b[1] : acc0b[0]);
    float v1 = (rsel ? acc1a[1] : acc1a[0]) + (rsel ? acc1b[1] : acc1b[0]);
    float v = csel ? v1 : v0;
    float th = tanh_fast(v);
    hbuf[cur][rsel][ocol] = f2bf(th);
    *outp = th; outp += HID;
    if (t == T_SEQ - 1) *hfinp = th;
    asm volatile("s_waitcnt lgkmcnt(0)\n\ts_barrier" ::: "memory");
  }
}

extern "C" void kernel_launch(void* const* d_in, const int* in_sizes, int n_in,
                              void* d_out, int out_size, void* d_ws, size_t ws_size,
                              hipStream_t stream) {
  const float* x  = (const float*)d_in[0];
  const float* Wx = (const float*)d_in[1];
  const float* Wh = (const float*)d_in[2];
  const float* bh = (const float*)d_in[3];
  float* out = (float*)d_out;
  (void)in_sizes; (void)n_in; (void)out_size;

  const size_t need = (size_t)512 * T_SEQ * HID * sizeof(unsigned short);  // 67 MB
  if (ws_size >= need) {
    unsigned short* xw = (unsigned short*)d_ws;
    xw_gemm_kernel<<<(512 * T_SEQ) / GROWS, 256, 0, stream>>>(x, Wx, bh, xw);
    rnn_rec_kernel<<<512 / BB, 256, 0, stream>>>(xw, Wh, out);
  } else {
    rnn_fused_fallback<<<512 / BB, 256, 0, stream>>>(x, Wx, Wh, bh, out);
  }
}